// Round 1
// baseline (655.175 us; speedup 1.0000x reference)
//
#include <hip/hip_runtime.h>
#include <math.h>

// Problem: B=131072 rows, C=1000 classes, fp32 logits.
// out = mean(2 - 2 * softmax(x)[i, tgt[i]])  -- a single fp32 scalar.
//
// Strategy: one wave (64 lanes) per row. 250 float4 per row -> 4 vec4
// loads/lane held in registers; single global pass (max + sum both from
// registers). Two-stage reduction through d_ws to avoid single-address
// atomic serialization.

constexpr int C_CLS = 1000;
constexpr int NV4 = C_CLS / 4;             // 250 float4 per row
constexpr int WAVES_PER_BLOCK = 4;         // 256 threads
constexpr int ROWS_PER_WAVE = 4;
constexpr int ROWS_PER_BLOCK = WAVES_PER_BLOCK * ROWS_PER_WAVE;  // 16

__global__ __launch_bounds__(256) void softmax_gather_kernel(
    const float* __restrict__ x, const int* __restrict__ tgt,
    float* __restrict__ partials, int B)
{
    const int lane = threadIdx.x & 63;
    const int wave = threadIdx.x >> 6;

    float acc = 0.0f;  // sum of p_target over this wave's rows
    const int row0 = blockIdx.x * ROWS_PER_BLOCK + wave * ROWS_PER_WAVE;

    for (int r = 0; r < ROWS_PER_WAVE; ++r) {
        const int row = row0 + r;
        if (row >= B) break;

        const float4* rp = reinterpret_cast<const float4*>(x + (size_t)row * C_CLS);

        float4 v[4];
        float m = -INFINITY;
        #pragma unroll
        for (int k = 0; k < 4; ++k) {
            const int idx = lane + 64 * k;
            if (idx < NV4) {
                v[k] = rp[idx];
                m = fmaxf(m, fmaxf(fmaxf(v[k].x, v[k].y), fmaxf(v[k].z, v[k].w)));
            }
        }
        // wave-reduce max over 64 lanes
        #pragma unroll
        for (int off = 32; off > 0; off >>= 1)
            m = fmaxf(m, __shfl_xor(m, off));

        float s = 0.0f;
        #pragma unroll
        for (int k = 0; k < 4; ++k) {
            const int idx = lane + 64 * k;
            if (idx < NV4) {
                s += __expf(v[k].x - m) + __expf(v[k].y - m)
                   + __expf(v[k].z - m) + __expf(v[k].w - m);
            }
        }
        // wave-reduce sum
        #pragma unroll
        for (int off = 32; off > 0; off >>= 1)
            s += __shfl_xor(s, off);

        if (lane == 0) {
            // target logit: L1-hot, this wave just pulled the row in
            const float xt = x[(size_t)row * C_CLS + tgt[row]];
            acc += __expf(xt - m) / s;
        }
    }

    __shared__ float sm[WAVES_PER_BLOCK];
    if (lane == 0) sm[wave] = acc;
    __syncthreads();
    if (threadIdx.x == 0) {
        float t = 0.0f;
        #pragma unroll
        for (int w = 0; w < WAVES_PER_BLOCK; ++w) t += sm[w];
        partials[blockIdx.x] = t;
    }
}

__global__ __launch_bounds__(1024) void finalize_kernel(
    const float* __restrict__ partials, int n, float* __restrict__ out, float invB)
{
    float s = 0.0f;
    for (int i = threadIdx.x; i < n; i += 1024) s += partials[i];
    #pragma unroll
    for (int off = 32; off > 0; off >>= 1) s += __shfl_xor(s, off);

    __shared__ float sm[16];
    const int lane = threadIdx.x & 63;
    const int wave = threadIdx.x >> 6;
    if (lane == 0) sm[wave] = s;
    __syncthreads();
    if (threadIdx.x == 0) {
        float t = 0.0f;
        #pragma unroll
        for (int w = 0; w < 16; ++w) t += sm[w];
        out[0] = 2.0f - 2.0f * t * invB;
    }
}

extern "C" void kernel_launch(void* const* d_in, const int* in_sizes, int n_in,
                              void* d_out, int out_size, void* d_ws, size_t ws_size,
                              hipStream_t stream)
{
    const float* x   = (const float*)d_in[0];
    const int*   tgt = (const int*)d_in[1];
    float*       out = (float*)d_out;
    float*       partials = (float*)d_ws;

    const int B = in_sizes[1];                       // 131072
    const int grid = (B + ROWS_PER_BLOCK - 1) / ROWS_PER_BLOCK;  // 8192

    softmax_gather_kernel<<<grid, 256, 0, stream>>>(x, tgt, partials, B);
    finalize_kernel<<<1, 1024, 0, stream>>>(partials, grid, out, 1.0f / (float)B);
}